// Round 7
// baseline (191.776 us; speedup 1.0000x reference)
//
#include <hip/hip_runtime.h>

// CrumbReconstructor via split-bf16 MFMA + exact fp32 resolution.
//
// D-space: D(key,row) ~= BIAS + (d_true - knorm)  (knorm const per key, so
// argmin is preserved).  MFMA 16x16x32 bf16, K=32 encoding:
//   A(key) = [-2k_hi(8) | -2k_hi(8) | -2k_lo(8) | 1,1,0...]
//   B(row) = [ m_hi(8)  |  m_lo(8)  |  m_hi(8)  | bm_hi,bm_lo,0...]
// bm = BIAS + mnorm (bf16 hi+lo split).  BIAS=1024: contending D values sit
// near 1024 (ulp 2^-13) so the 8-bit idx clobber costs <=0.031; total error
// per CONTENDING row eps <= ~0.15 (bm-split + missing k_lo*m_lo + fp32 accum).
// R6 bug fixed: all-zero codebook rows have d_true = knorm -> D-space BIAS
// exactly (NOT BIAS+knorm).  First zero row n0 injected with value 1024.0.
//
// Exactness: pack idx in low 8 bits (monotone for positive floats); track
// top-THREE per key.  gap(m1,m2) > w=0.5 >= 2eps  -> m1's idx is provably the
// fp32 argmin (strict).  Else if gap(m1,m3) > w -> exact fp32 compare of c1
// vs c2 only (bit-identical R0 formula, lower index wins ties).  Else (rare):
// full 256-row exact rescan.  Zero rows are +inf in the approx pass and
// appear naturally (d=knorm) in the exact paths.
//
// Layouts (verified by R6 near-correctness + learn_hip m89):
//   A[m=lane&15][k=quad*8+j], B[k=quad*8+j][n=lane&15], D[m=quad*4+reg][n=lane&15]

#define NROW   256
#define LBLK   8
#define BLOCKT 256           // 4 waves
#define TILES_PER_WAVE 2     // 128 keys/wave; grid 1568 exact
#define BIASF  1024.0f
#define WINDOW 0.5f

typedef __attribute__((ext_vector_type(8))) short bf16x8;
typedef __attribute__((ext_vector_type(4))) float f32x4;

__device__ __forceinline__ unsigned bf16_rne(float f) {
    unsigned u = __float_as_uint(f);
    return (u + 0x7FFFu + ((u >> 16) & 1u)) >> 16;
}
__device__ __forceinline__ bf16x8 as_bf16x8(int4 v) {
    union { int4 i; bf16x8 b; } u; u.i = v; return u.b;
}
template<int SH>
__device__ __forceinline__ int dppror(int v) {   // rotate within 16-lane row
    return __builtin_amdgcn_update_dpp(v, v, 0x120 | SH, 0xF, 0xF, false);
}
// merge two sorted triples (this lane's and the rotated one's) -> top-3
template<int SH>
__device__ __forceinline__ void merge3(int& m1, int& m2, int& m3) {
    int b1 = dppror<SH>(m1), b2 = dppror<SH>(m2), b3 = dppror<SH>(m3);
    int x = min(m1, b1), y = max(m1, b1);
    int p = min(m2, b2), q = max(m2, b2);
    m3 = min(min(max(y, p), q), min(m3, b3));
    m1 = x;
    m2 = min(y, p);
}
__device__ __forceinline__ int sel4(int v0, int v1, int v2, int v3, int i) {
    int r = v0;
    r = (i == 1) ? v1 : r;
    r = (i == 2) ? v2 : r;
    r = (i == 3) ? v3 : r;
    return r;
}
// bit-identical R0 distance: seq-fma dot, fmaf(dot,-2,kn)+nrm  (absmax 0.0)
__device__ __forceinline__ float exact_d(float4 ka, float4 kb, float kn,
                                         const float* rp, float nrm) {
    const float4 ra = ((const float4*)rp)[0];
    const float4 rb = ((const float4*)rp)[1];
    float dot = ka.x * ra.x;
    dot = fmaf(ka.y, ra.y, dot);
    dot = fmaf(ka.z, ra.z, dot);
    dot = fmaf(ka.w, ra.w, dot);
    dot = fmaf(kb.x, rb.x, dot);
    dot = fmaf(kb.y, rb.y, dot);
    dot = fmaf(kb.z, rb.z, dot);
    dot = fmaf(kb.w, rb.w, dot);
    return fmaf(dot, -2.0f, kn) + nrm;
}

// ---------- prep: ws layout (floats): [0,2048) hi|lo 8/row ; [2048,2304) bm
// packed bf16 pair ; [2304,2560) mnorm ; [2560] n0 ----------
__global__ __launch_bounds__(NROW) void prep_kernel(const float* __restrict__ mem,
                                                    float* __restrict__ ws) {
    int r = threadIdx.x;
    int* n0p = (int*)(ws + 2560);
    if (r == 0) *n0p = 0x7FFFFFFF;
    __syncthreads();

    const float4* g = (const float4*)(mem + r * LBLK);
    float4 a = g[0], b = g[1];
    float q0=a.x*a.x,q1=a.y*a.y,q2=a.z*a.z,q3=a.w*a.w;
    float q4=b.x*b.x,q5=b.y*b.y,q6=b.z*b.z,q7=b.w*b.w;
    float mn = ((q0+q1)+(q2+q3))+((q4+q5)+(q6+q7));   // numpy tree order
    ws[2304 + r] = mn;

    float v[8] = {a.x,a.y,a.z,a.w,b.x,b.y,b.z,b.w};
    unsigned h[8], l[8];
    #pragma unroll
    for (int i = 0; i < 8; ++i) {
        h[i] = bf16_rne(v[i]);
        l[i] = bf16_rne(v[i] - __uint_as_float(h[i] << 16));
    }
    unsigned* o = (unsigned*)(ws + r * 8);
    o[0] = h[0]|(h[1]<<16); o[1] = h[2]|(h[3]<<16);
    o[2] = h[4]|(h[5]<<16); o[3] = h[6]|(h[7]<<16);
    o[4] = l[0]|(l[1]<<16); o[5] = l[2]|(l[3]<<16);
    o[6] = l[4]|(l[5]<<16); o[7] = l[6]|(l[7]<<16);

    unsigned bm0;
    if (mn == 0.0f) {                 // all-zero row: +inf in approx pass
        bm0 = 0x7F80u;                // bf16 +inf (k=24 slot), 0 elsewhere
        atomicMin(n0p, r);
    } else {
        float bv = BIASF + mn;
        unsigned bh = bf16_rne(bv);
        unsigned bl = bf16_rne(bv - __uint_as_float(bh << 16));
        bm0 = bh | (bl << 16);
    }
    ((unsigned*)(ws + 2048))[r] = bm0;
}

__global__ __launch_bounds__(BLOCKT, 4) void crumb_kernel(
    const float* __restrict__ x, const float* __restrict__ mem,
    const float* __restrict__ ws, float* __restrict__ out, int nblocks)
{
    __shared__ float s_cb32[NROW * LBLK];    // 8 KB fp32 codebook (exact paths + gather)
    __shared__ float s_mnorm[NROW];          // 1 KB
    __shared__ float s_keyhilo[4][64 * 8];   // 8 KB: A-frag pages, 32B/key
    __shared__ float s_keyf32[4][64 * 8];    // 8 KB
    __shared__ float s_knorm[4][64];
    __shared__ int   s_idx[4][16];

    const int tid = threadIdx.x;
    {
        const float4* g = (const float4*)mem;
        float4* s = (float4*)s_cb32;
        s[tid]       = g[tid];
        s[tid + 256] = g[tid + 256];
        s_mnorm[tid] = ws[2304 + tid];
    }
    __syncthreads();
    const int n0 = *(const int*)(ws + 2560);

    const int wave = tid >> 6;
    const int lane = tid & 63;
    const int l15  = lane & 15;
    const int quad = lane >> 4;

    // ---- B fragments (whole kernel resident; loaded once from global ws) ----
    int4 Bfrag[16];
    if (quad == 3) {
        #pragma unroll
        for (int t = 0; t < 16; ++t) {
            unsigned bm0 = ((const unsigned*)(ws + 2048))[16 * t + l15];
            Bfrag[t] = make_int4((int)bm0, 0, 0, 0);
        }
    } else {
        const float* base = ws + l15 * 8 + (quad == 1 ? 4 : 0);
        #pragma unroll
        for (int t = 0; t < 16; ++t)
            Bfrag[t] = *(const int4*)(base + t * 128);
    }

    const long wave_global = (long)blockIdx.x * 4 + wave;
    const long keybase0 = wave_global * (64 * TILES_PER_WAVE);

    for (int tile = 0; tile < TILES_PER_WAVE; ++tile) {
        const long kb = keybase0 + (long)tile * 64;

        // ---- stage this wave's 64 keys ----
        {
            long key = kb + lane;
            long kk = key < nblocks ? key : (long)nblocks - 1;
            const float4* xp = (const float4*)(x + kk * LBLK);
            float4 xa = xp[0], xb = xp[1];
            float q0=xa.x*xa.x,q1=xa.y*xa.y,q2=xa.z*xa.z,q3=xa.w*xa.w;
            float q4=xb.x*xb.x,q5=xb.y*xb.y,q6=xb.z*xb.z,q7=xb.w*xb.w;
            s_knorm[wave][lane] = ((q0+q1)+(q2+q3))+((q4+q5)+(q6+q7));
            float4* kfp = (float4*)&s_keyf32[wave][lane * 8];
            kfp[0] = xa; kfp[1] = xb;
            float v[8] = {xa.x,xa.y,xa.z,xa.w,xb.x,xb.y,xb.z,xb.w};
            unsigned h[8], l[8];
            #pragma unroll
            for (int i = 0; i < 8; ++i) {
                float nv = -2.0f * v[i];                 // exact
                h[i] = bf16_rne(nv);
                l[i] = bf16_rne(nv - __uint_as_float(h[i] << 16));
            }
            uint4* kh = (uint4*)&s_keyhilo[wave][lane * 8];
            kh[0] = make_uint4(h[0]|(h[1]<<16), h[2]|(h[3]<<16),
                               h[4]|(h[5]<<16), h[6]|(h[7]<<16));
            kh[1] = make_uint4(l[0]|(l[1]<<16), l[2]|(l[3]<<16),
                               l[4]|(l[5]<<16), l[6]|(l[7]<<16));
        }

        for (int s = 0; s < 4; ++s) {
            // A fragment: quads 0,1 = hi, quad 2 = lo, quad 3 = [1,1,0...]
            int4 Afrag;
            if (quad == 3) Afrag = make_int4(0x3F803F80, 0, 0, 0);
            else Afrag = *(const int4*)&s_keyhilo[wave][(16*s + l15)*8 + (quad==2 ? 4:0)];

            int m1[4], m2[4], m3[4];
            #pragma unroll
            for (int rr = 0; rr < 4; ++rr) { m1[rr]=m2[rr]=m3[rr]=0x7FFFFFFF; }
            const f32x4 zacc = {0.f, 0.f, 0.f, 0.f};

            #pragma unroll
            for (int t = 0; t < 16; ++t) {
                f32x4 D = __builtin_amdgcn_mfma_f32_16x16x32_bf16(
                    as_bf16x8(Afrag), as_bf16x8(Bfrag[t]), zacc, 0, 0, 0);
                #pragma unroll
                for (int rr = 0; rr < 4; ++rr) {
                    int u = (int)((__float_as_uint(D[rr]) & 0xFFFFFF00u)
                                  | (unsigned)((t << 4) | l15));
                    int a = max(u, m1[rr]); m1[rr] = min(u, m1[rr]);
                    int b = max(a, m2[rr]); m2[rr] = min(a, m2[rr]);
                    m3[rr] = min(b, m3[rr]);
                }
            }
            // baseline: first all-zero row, D-space value = BIAS exactly
            if (n0 != 0x7FFFFFFF && l15 == 0) {
                const int ub = (int)(0x44800000u | (unsigned)n0);  // bits(1024.0f)|n0
                #pragma unroll
                for (int rr = 0; rr < 4; ++rr) {
                    int a = max(ub, m1[rr]); m1[rr] = min(ub, m1[rr]);
                    int b = max(a, m2[rr]);  m2[rr] = min(a, m2[rr]);
                    m3[rr] = min(b, m3[rr]);
                }
            }
            // 16-lane top-3 merge (disjoint rotation windows -> exact)
            #pragma unroll
            for (int rr = 0; rr < 4; ++rr) {
                merge3<1>(m1[rr], m2[rr], m3[rr]);
                merge3<2>(m1[rr], m2[rr], m3[rr]);
                merge3<4>(m1[rr], m2[rr], m3[rr]);
                merge3<8>(m1[rr], m2[rr], m3[rr]);
            }

            // thresholds + fast-path default write
            int tintv[4];
            #pragma unroll
            for (int rr = 0; rr < 4; ++rr) {
                float tf = __uint_as_float((unsigned)m1[rr] & 0xFFFFFF00u) + WINDOW;
                tintv[rr] = (int)(__float_as_uint(tf) | 0xFFu);
                if (l15 == rr) s_idx[wave][quad * 4 + rr] = m1[rr] & 0xFF;
            }

            // lane-parallel exact pair resolve (slow2 && !need3), 4 keys/quad
            {
                const int rsel = l15 & 3;
                int a1 = sel4(m1[0],m1[1],m1[2],m1[3], rsel);
                int a2 = sel4(m2[0],m2[1],m2[2],m2[3], rsel);
                int a3 = sel4(m3[0],m3[1],m3[2],m3[3], rsel);
                int tt = sel4(tintv[0],tintv[1],tintv[2],tintv[3], rsel);
                if (l15 < 4 && a2 <= tt && a3 > tt) {
                    int c1 = a1 & 0xFF, c2 = a2 & 0xFF;
                    const int keyloc = 16*s + quad*4 + rsel;
                    const float4* kf = (const float4*)&s_keyf32[wave][keyloc * 8];
                    float4 ka = kf[0], kbv = kf[1];
                    float kn = s_knorm[wave][keyloc];
                    float d1 = exact_d(ka, kbv, kn, &s_cb32[c1*8], s_mnorm[c1]);
                    float d2 = exact_d(ka, kbv, kn, &s_cb32[c2*8], s_mnorm[c2]);
                    int wn = (d2 < d1) ? c2 : ((d2 == d1) ? min(c1, c2) : c1);
                    s_idx[wave][quad * 4 + rsel] = wn;
                }
            }

            // rare: 3-way contention -> exact full rescan (quad-cooperative)
            #pragma unroll
            for (int rr = 0; rr < 4; ++rr) {
                if (m3[rr] <= tintv[rr]) {            // quad-uniform
                    const int keyloc = 16*s + quad*4 + rr;
                    const float4* kf = (const float4*)&s_keyf32[wave][keyloc * 8];
                    float4 ka = kf[0], kbv = kf[1];
                    float kn = s_knorm[wave][keyloc];
                    float bd = __int_as_float(0x7F800000); int bn = 0x3FF;
                    for (int rw = 0; rw < 16; ++rw) {
                        int nn = rw * 16 + l15;       // ascending per lane
                        float d = exact_d(ka, kbv, kn, &s_cb32[nn*8], s_mnorm[nn]);
                        bool take = (d < bd);
                        bd = take ? d : bd; bn = take ? nn : bn;
                    }
                    // lexicographic (d, n) min across the quad's 16 lanes
                    #pragma unroll
                    for (int st = 0; st < 4; ++st) {
                        int od_i, on;
                        if (st == 0)      { od_i = dppror<1>(__float_as_int(bd)); on = dppror<1>(bn); }
                        else if (st == 1) { od_i = dppror<2>(__float_as_int(bd)); on = dppror<2>(bn); }
                        else if (st == 2) { od_i = dppror<4>(__float_as_int(bd)); on = dppror<4>(bn); }
                        else              { od_i = dppror<8>(__float_as_int(bd)); on = dppror<8>(bn); }
                        float od = __int_as_float(od_i);
                        bool take = (od < bd) || (od == bd && on < bn);
                        bd = take ? od : bd; bn = take ? on : bn;
                    }
                    if (l15 == rr) s_idx[wave][quad * 4 + rr] = bn;
                }
            }

            // epilogue: gather winning rows from LDS, store
            if (lane < 16) {
                long key = kb + 16 * s + lane;
                if (key < nblocks) {
                    int nn = s_idx[wave][lane];
                    const float4* rp = (const float4*)&s_cb32[nn * 8];
                    float4 o0 = rp[0], o1 = rp[1];
                    float4* op = (float4*)(out + key * LBLK);
                    op[0] = o0; op[1] = o1;
                }
            }
        }
    }
}

extern "C" void kernel_launch(void* const* d_in, const int* in_sizes, int n_in,
                              void* d_out, int out_size, void* d_ws, size_t ws_size,
                              hipStream_t stream) {
    const float* x   = (const float*)d_in[0];
    const float* mem = (const float*)d_in[1];
    float* out = (float*)d_out;
    float* ws  = (float*)d_ws;   // needs 2561 floats

    int n = in_sizes[0];
    int nblocks = n / LBLK;                                   // 802816
    int keys_per_block = 4 * 64 * TILES_PER_WAVE;             // 512
    int grid = (nblocks + keys_per_block - 1) / keys_per_block;  // 1568 exact

    hipLaunchKernelGGL(prep_kernel, dim3(1), dim3(NROW), 0, stream, mem, ws);
    hipLaunchKernelGGL(crumb_kernel, dim3(grid), dim3(BLOCKT), 0, stream,
                       x, mem, ws, out, nblocks);
}

// Round 8
// 187.412 us; speedup vs baseline: 1.0233x; 1.0233x over previous
//
#include <hip/hip_runtime.h>

// CrumbReconstructor via split-bf16 MFMA + exact fp32 resolution.  (R8)
//
// Algorithm identical to R7 (passed, absmax 0.0).  R7 post-mortem: 16
// resident B-fragments (64 VGPR) spilled to scratch (+39MB HBM writes).
// R8: B-fragments staged once in LDS (16 KB, shared by all 4 waves) and
// re-read per MFMA (ds_read_b128 ~12cyc, hidden under the ~48cyc fold);
// s_keyf32 dropped (exact paths re-read x from global, L2-hot); epilogue
// coalesced over all 64 lanes.  VGPR demand ~50 -> no spills.
//
// D-space: D(key,row) ~= BIAS + (d_true - knorm), BIAS=1024.  MFMA 16x16x32:
//   A(key) = [-2k_hi | -2k_hi | -2k_lo | 1,1,0...]
//   B(row) = [ m_hi  |  m_lo  |  m_hi  | bm_hi,bm_lo,0...],  bm = BIAS+mnorm
// idx packed in low 8 bits of D bits (monotone, all D>0).  Track top-3.
//   gap(m1,m2) > 0.5 -> provably exact argmin
//   else gap(m1,m3) > 0.5 -> exact fp32 compare c1 vs c2 (R0 formula)
//   else -> full 256-row exact rescan (rare)
// Zero rows: +inf in approx pass; first such row n0 injected at BIAS exactly.

#define NROW   256
#define LBLK   8
#define BLOCKT 256           // 4 waves
#define TILES_PER_WAVE 2     // 128 keys/wave; grid 1568 exact
#define BIASF  1024.0f
#define WINDOW 0.5f

typedef __attribute__((ext_vector_type(8))) short bf16x8;
typedef __attribute__((ext_vector_type(4))) float f32x4;

__device__ __forceinline__ unsigned bf16_rne(float f) {
    unsigned u = __float_as_uint(f);
    return (u + 0x7FFFu + ((u >> 16) & 1u)) >> 16;
}
__device__ __forceinline__ bf16x8 as_bf16x8(int4 v) {
    union { int4 i; bf16x8 b; } u; u.i = v; return u.b;
}
template<int SH>
__device__ __forceinline__ int dppror(int v) {   // rotate within 16-lane row
    return __builtin_amdgcn_update_dpp(v, v, 0x120 | SH, 0xF, 0xF, false);
}
template<int SH>
__device__ __forceinline__ void merge3(int& m1, int& m2, int& m3) {
    int b1 = dppror<SH>(m1), b2 = dppror<SH>(m2), b3 = dppror<SH>(m3);
    int x = min(m1, b1), y = max(m1, b1);
    int p = min(m2, b2), q = max(m2, b2);
    m3 = min(min(max(y, p), q), min(m3, b3));
    m1 = x;
    m2 = min(y, p);
}
__device__ __forceinline__ int sel4(int v0, int v1, int v2, int v3, int i) {
    int r = v0;
    r = (i == 1) ? v1 : r;
    r = (i == 2) ? v2 : r;
    r = (i == 3) ? v3 : r;
    return r;
}
// bit-identical R0 distance (absmax 0.0 verified)
__device__ __forceinline__ float exact_d(float4 ka, float4 kb, float kn,
                                         const float* rp, float nrm) {
    const float4 ra = ((const float4*)rp)[0];
    const float4 rb = ((const float4*)rp)[1];
    float dot = ka.x * ra.x;
    dot = fmaf(ka.y, ra.y, dot);
    dot = fmaf(ka.z, ra.z, dot);
    dot = fmaf(ka.w, ra.w, dot);
    dot = fmaf(kb.x, rb.x, dot);
    dot = fmaf(kb.y, rb.y, dot);
    dot = fmaf(kb.z, rb.z, dot);
    dot = fmaf(kb.w, rb.w, dot);
    return fmaf(dot, -2.0f, kn) + nrm;
}

// ---------- prep (unchanged from R7): ws floats
// [0,2048) hi|lo 8/row ; [2048,2304) bm packed ; [2304,2560) mnorm ; [2560] n0
__global__ __launch_bounds__(NROW) void prep_kernel(const float* __restrict__ mem,
                                                    float* __restrict__ ws) {
    int r = threadIdx.x;
    int* n0p = (int*)(ws + 2560);
    if (r == 0) *n0p = 0x7FFFFFFF;
    __syncthreads();

    const float4* g = (const float4*)(mem + r * LBLK);
    float4 a = g[0], b = g[1];
    float q0=a.x*a.x,q1=a.y*a.y,q2=a.z*a.z,q3=a.w*a.w;
    float q4=b.x*b.x,q5=b.y*b.y,q6=b.z*b.z,q7=b.w*b.w;
    float mn = ((q0+q1)+(q2+q3))+((q4+q5)+(q6+q7));   // numpy tree order
    ws[2304 + r] = mn;

    float v[8] = {a.x,a.y,a.z,a.w,b.x,b.y,b.z,b.w};
    unsigned h[8], l[8];
    #pragma unroll
    for (int i = 0; i < 8; ++i) {
        h[i] = bf16_rne(v[i]);
        l[i] = bf16_rne(v[i] - __uint_as_float(h[i] << 16));
    }
    unsigned* o = (unsigned*)(ws + r * 8);
    o[0] = h[0]|(h[1]<<16); o[1] = h[2]|(h[3]<<16);
    o[2] = h[4]|(h[5]<<16); o[3] = h[6]|(h[7]<<16);
    o[4] = l[0]|(l[1]<<16); o[5] = l[2]|(l[3]<<16);
    o[6] = l[4]|(l[5]<<16); o[7] = l[6]|(l[7]<<16);

    unsigned bm0;
    if (mn == 0.0f) {                 // all-zero row: +inf in approx pass
        bm0 = 0x7F80u;
        atomicMin(n0p, r);
    } else {
        float bv = BIASF + mn;
        unsigned bh = bf16_rne(bv);
        unsigned bl = bf16_rne(bv - __uint_as_float(bh << 16));
        bm0 = bh | (bl << 16);
    }
    ((unsigned*)(ws + 2048))[r] = bm0;
}

__global__ __launch_bounds__(BLOCKT, 4) void crumb_kernel(
    const float* __restrict__ x, const float* __restrict__ mem,
    const float* __restrict__ ws, float* __restrict__ out, int nblocks)
{
    __shared__ float s_cb32[NROW * LBLK];    // 8 KB (exact paths + gather)
    __shared__ float s_mnorm[NROW];          // 1 KB
    __shared__ int4  s_B[16 * 64];           // 16 KB: B-frag per (t, lane)
    __shared__ float s_keyhilo[4][64 * 8];   // 8 KB: A-frag pages, 32B/key
    __shared__ float s_knorm[4][64];         // 1 KB
    __shared__ int   s_idx[4][64];           // 1 KB

    const int tid = threadIdx.x;
    {
        const float4* g = (const float4*)mem;
        ((float4*)s_cb32)[tid]       = g[tid];
        ((float4*)s_cb32)[tid + 256] = g[tid + 256];
        s_mnorm[tid] = ws[2304 + tid];
    }
    // stage B fragments: frag(t, lane): quad<3 -> hi/lo page of row 16t+l15,
    // quad3 -> (bm,0,0,0)
    for (int i = tid; i < 16 * 64; i += BLOCKT) {
        int t = i >> 6, l = i & 63, q = l >> 4, p = l & 15;
        int4 f;
        if (q == 3) f = make_int4((int)((const unsigned*)(ws + 2048))[16*t + p], 0, 0, 0);
        else        f = *(const int4*)(ws + (16*t + p) * 8 + (q == 1 ? 4 : 0));
        s_B[i] = f;
    }
    __syncthreads();
    const int n0 = *(const int*)(ws + 2560);

    const int wave = tid >> 6;
    const int lane = tid & 63;
    const int l15  = lane & 15;
    const int quad = lane >> 4;

    const long wave_global = (long)blockIdx.x * 4 + wave;
    const long keybase0 = wave_global * (64 * TILES_PER_WAVE);

    for (int tile = 0; tile < TILES_PER_WAVE; ++tile) {
        const long kb = keybase0 + (long)tile * 64;

        // ---- stage this wave's 64 keys (A-frag pages + knorm) ----
        {
            long key = kb + lane;
            long kk = key < nblocks ? key : (long)nblocks - 1;
            const float4* xp = (const float4*)(x + kk * LBLK);
            float4 xa = xp[0], xb = xp[1];
            float q0=xa.x*xa.x,q1=xa.y*xa.y,q2=xa.z*xa.z,q3=xa.w*xa.w;
            float q4=xb.x*xb.x,q5=xb.y*xb.y,q6=xb.z*xb.z,q7=xb.w*xb.w;
            s_knorm[wave][lane] = ((q0+q1)+(q2+q3))+((q4+q5)+(q6+q7));
            float v[8] = {xa.x,xa.y,xa.z,xa.w,xb.x,xb.y,xb.z,xb.w};
            unsigned h[8], l[8];
            #pragma unroll
            for (int i = 0; i < 8; ++i) {
                float nv = -2.0f * v[i];                 // exact
                h[i] = bf16_rne(nv);
                l[i] = bf16_rne(nv - __uint_as_float(h[i] << 16));
            }
            uint4* kh = (uint4*)&s_keyhilo[wave][lane * 8];
            kh[0] = make_uint4(h[0]|(h[1]<<16), h[2]|(h[3]<<16),
                               h[4]|(h[5]<<16), h[6]|(h[7]<<16));
            kh[1] = make_uint4(l[0]|(l[1]<<16), l[2]|(l[3]<<16),
                               l[4]|(l[5]<<16), l[6]|(l[7]<<16));
        }

        for (int s = 0; s < 4; ++s) {
            // A fragment: quads 0,1 = hi, quad 2 = lo, quad 3 = [1,1,0...]
            int4 araw = *(const int4*)&s_keyhilo[wave][(16*s + l15)*8 + (quad==2 ? 4:0)];
            int4 Afrag = (quad == 3) ? make_int4(0x3F803F80, 0, 0, 0) : araw;

            int m1[4], m2[4], m3[4];
            #pragma unroll
            for (int rr = 0; rr < 4; ++rr) { m1[rr]=m2[rr]=m3[rr]=0x7FFFFFFF; }
            const f32x4 zacc = {0.f, 0.f, 0.f, 0.f};

            #pragma unroll
            for (int t = 0; t < 16; ++t) {
                int4 braw = s_B[t * 64 + lane];          // ds_read_b128
                f32x4 D = __builtin_amdgcn_mfma_f32_16x16x32_bf16(
                    as_bf16x8(Afrag), as_bf16x8(braw), zacc, 0, 0, 0);
                #pragma unroll
                for (int rr = 0; rr < 4; ++rr) {
                    int u = (int)((__float_as_uint(D[rr]) & 0xFFFFFF00u)
                                  | (unsigned)((t << 4) | l15));
                    int a = max(u, m1[rr]); m1[rr] = min(u, m1[rr]);
                    int b = max(a, m2[rr]); m2[rr] = min(a, m2[rr]);
                    m3[rr] = min(b, m3[rr]);
                }
            }
            // baseline: first all-zero row, D-space value = BIAS exactly
            if (n0 != 0x7FFFFFFF && l15 == 0) {
                const int ub = (int)(0x44800000u | (unsigned)n0);  // bits(1024.f)|n0
                #pragma unroll
                for (int rr = 0; rr < 4; ++rr) {
                    int a = max(ub, m1[rr]); m1[rr] = min(ub, m1[rr]);
                    int b = max(a, m2[rr]);  m2[rr] = min(a, m2[rr]);
                    m3[rr] = min(b, m3[rr]);
                }
            }
            // 16-lane top-3 merge
            #pragma unroll
            for (int rr = 0; rr < 4; ++rr) {
                merge3<1>(m1[rr], m2[rr], m3[rr]);
                merge3<2>(m1[rr], m2[rr], m3[rr]);
                merge3<4>(m1[rr], m2[rr], m3[rr]);
                merge3<8>(m1[rr], m2[rr], m3[rr]);
            }

            // thresholds + fast-path default write
            int tintv[4];
            #pragma unroll
            for (int rr = 0; rr < 4; ++rr) {
                float tf = __uint_as_float((unsigned)m1[rr] & 0xFFFFFF00u) + WINDOW;
                tintv[rr] = (int)(__float_as_uint(tf) | 0xFFu);
                if (l15 == rr) s_idx[wave][16*s + quad*4 + rr] = m1[rr] & 0xFF;
            }

            // lane-parallel exact pair resolve (2 contenders), 4 keys/quad
            {
                const int rsel = l15 & 3;
                int a1 = sel4(m1[0],m1[1],m1[2],m1[3], rsel);
                int a2 = sel4(m2[0],m2[1],m2[2],m2[3], rsel);
                int a3 = sel4(m3[0],m3[1],m3[2],m3[3], rsel);
                int tt = sel4(tintv[0],tintv[1],tintv[2],tintv[3], rsel);
                if (l15 < 4 && a2 <= tt && a3 > tt) {
                    int c1 = a1 & 0xFF, c2 = a2 & 0xFF;
                    const int keyloc = 16*s + quad*4 + rsel;
                    long key = kb + keyloc;
                    long kk = key < nblocks ? key : (long)nblocks - 1;
                    const float4* kf = (const float4*)(x + kk * LBLK);
                    float4 ka = kf[0], kbv = kf[1];
                    float kn = s_knorm[wave][keyloc];
                    float d1 = exact_d(ka, kbv, kn, &s_cb32[c1*8], s_mnorm[c1]);
                    float d2 = exact_d(ka, kbv, kn, &s_cb32[c2*8], s_mnorm[c2]);
                    int wn = (d2 < d1) ? c2 : ((d2 == d1) ? min(c1, c2) : c1);
                    s_idx[wave][keyloc] = wn;
                }
            }

            // rare: 3-way contention -> exact full rescan (quad-cooperative)
            #pragma unroll
            for (int rr = 0; rr < 4; ++rr) {
                if (m3[rr] <= tintv[rr]) {            // quad-uniform
                    const int keyloc = 16*s + quad*4 + rr;
                    long key = kb + keyloc;
                    long kk = key < nblocks ? key : (long)nblocks - 1;
                    const float4* kf = (const float4*)(x + kk * LBLK);
                    float4 ka = kf[0], kbv = kf[1];
                    float kn = s_knorm[wave][keyloc];
                    float bd = __int_as_float(0x7F800000); int bn = 0x3FF;
                    for (int rw = 0; rw < 16; ++rw) {
                        int nn = rw * 16 + l15;       // ascending per lane
                        float d = exact_d(ka, kbv, kn, &s_cb32[nn*8], s_mnorm[nn]);
                        bool take = (d < bd);
                        bd = take ? d : bd; bn = take ? nn : bn;
                    }
                    #pragma unroll
                    for (int st = 0; st < 4; ++st) {
                        int od_i, on;
                        if (st == 0)      { od_i = dppror<1>(__float_as_int(bd)); on = dppror<1>(bn); }
                        else if (st == 1) { od_i = dppror<2>(__float_as_int(bd)); on = dppror<2>(bn); }
                        else if (st == 2) { od_i = dppror<4>(__float_as_int(bd)); on = dppror<4>(bn); }
                        else              { od_i = dppror<8>(__float_as_int(bd)); on = dppror<8>(bn); }
                        float od = __int_as_float(od_i);
                        bool take = (od < bd) || (od == bd && on < bn);
                        bd = take ? od : bd; bn = take ? on : bn;
                    }
                    if (l15 == rr) s_idx[wave][keyloc] = bn;
                }
            }
        }

        // ---- epilogue: all 64 lanes, coalesced gather+store ----
        {
            long key = kb + lane;
            if (key < nblocks) {
                int nn = s_idx[wave][lane];
                const float4* rp = (const float4*)&s_cb32[nn * 8];
                float4 o0 = rp[0], o1 = rp[1];
                float4* op = (float4*)(out + key * LBLK);
                op[0] = o0; op[1] = o1;
            }
        }
    }
}

extern "C" void kernel_launch(void* const* d_in, const int* in_sizes, int n_in,
                              void* d_out, int out_size, void* d_ws, size_t ws_size,
                              hipStream_t stream) {
    const float* x   = (const float*)d_in[0];
    const float* mem = (const float*)d_in[1];
    float* out = (float*)d_out;
    float* ws  = (float*)d_ws;   // 2561 floats

    int n = in_sizes[0];
    int nblocks = n / LBLK;                                   // 802816
    int keys_per_block = 4 * 64 * TILES_PER_WAVE;             // 512
    int grid = (nblocks + keys_per_block - 1) / keys_per_block;  // 1568 exact

    hipLaunchKernelGGL(prep_kernel, dim3(1), dim3(NROW), 0, stream, mem, ws);
    hipLaunchKernelGGL(crumb_kernel, dim3(grid), dim3(BLOCKT), 0, stream,
                       x, mem, ws, out, nblocks);
}